// Round 13
// baseline (359.788 us; speedup 1.0000x reference)
//
#include <hip/hip_runtime.h>
#include <hip/hip_fp16.h>
#include <math.h>

#define NU_    100000
#define NI_    50000
#define NB_    20000
#define DIM    64
#define E_UI_  2000000
#define E_BI_  600000
#define NPROP  (2 * E_UI_)
#define NTOT   (NU_ + NI_)
#define BATCH  4096
#define NBIN_P ((NTOT + 255) / 256)   // 586
#define NBIN_B ((NB_  + 255) / 256)   // 79

// Private-cell multisplit geometry: binned[bin][block][slot].
#define VG_P     512
#define SLICE_P  40
#define BINSZ_P  (VG_P * SLICE_P)     // 20480 slots per P bin
#define VG_B     96
#define SLICE_B  160
#define BINSZ_B  (VG_B * SLICE_B)     // 15360 slots per B bin
// Bin populations are HETEROGENEOUS (lesson from R4/R5 crash):
//   user bins:  5120 +- 71, item bins: 10240 +- 101, B bins: 7680 +- 87
// EBUF_CAP must exceed the ITEM-bin tail: 12288 = 10240 + 20 sigma (proven).
#define EBUF_CAP 12288

// Column-chunk ordering for gather locality: granule 16384 rows = 2 MB.
#define CHK_SH   14
#define NCHK     ((NTOT >> CHK_SH) + 1)   // 10
#define CSTRIDE  11                       // padded row stride

// Heavy-bins-first grid order for bin_csr: [B(79), item(196), user(390)]
#define NITEMBIN 196
#define NUSERBIN 390

#define MS_TOTAL    (VG_B + VG_P)     // 608 multisplit blocks (all co-resident)
#define CAST_BLOCKS 2048              // grid-stride streaming cast, no LDS
#define SCORE_BLOCKS (BATCH / 2)      // 2048: one wave per (sample,bundle)

// Layer2 only needs rows that score reads: all items + the sampled users.
#define NROW2 (NI_ + BATCH)

// fp8 gather payload scale: g values std ~8e-4 are subnormal-adjacent in
// e5m2 (min normal 6.1e-5); x64 centers them in the normal range. The 64
// folds exactly through both layers (f1s8 stores 64*f1_true).
#define FP8SC   64.0f
#define FP8ISC  (1.0f / 64.0f)

// ---------------------------------------------------------------------------
// bf16 helpers
__device__ __forceinline__ float bflo(unsigned int u) {
    return __uint_as_float(u << 16);
}
__device__ __forceinline__ float bfhi(unsigned int u) {
    return __uint_as_float(u & 0xFFFF0000u);
}
__device__ __forceinline__ unsigned short f2bf(float f) {         // RNE
    unsigned int u = __float_as_uint(f);
    u += 0x7FFFu + ((u >> 16) & 1u);
    return (unsigned short)(u >> 16);
}
__device__ __forceinline__ unsigned int pack2(float a, float b) {
    return (unsigned int)f2bf(a) | ((unsigned int)f2bf(b) << 16);
}

// ---------------------------------------------------------------------------
// e5m2 helpers: an e5m2 byte IS the top byte of an f16.
__device__ __forceinline__ float e5b(unsigned int hbits) {   // hbits = f16 bits
    return __half2float(__ushort_as_half((unsigned short)hbits));
}
__device__ __forceinline__ unsigned int f2e5(float f) {      // RNE via f16
    unsigned short u = __half_as_ushort(__float2half(f));    // RNE to f16
    u = (unsigned short)(u + 0x7Fu + ((u >> 8) & 1u));       // RNE to top byte
    return (unsigned int)(u >> 8);
}
// decode 8 e5m2 bytes (uint2) and accumulate
__device__ __forceinline__ void add8f8(float* s, uint2 x) {
    s[0] += e5b((x.x << 8)  & 0xFF00u);
    s[1] += e5b( x.x        & 0xFF00u);
    s[2] += e5b((x.x >> 8)  & 0xFF00u);
    s[3] += e5b((x.x >> 16) & 0xFF00u);
    s[4] += e5b((x.y << 8)  & 0xFF00u);
    s[5] += e5b( x.y        & 0xFF00u);
    s[6] += e5b((x.y >> 8)  & 0xFF00u);
    s[7] += e5b((x.y >> 16) & 0xFF00u);
}

// ---------------------------------------------------------------------------
// Streaming bf16 cast, SPLIT OUT of the multisplit kernel (R12 post-mortem:
// cast blocks inherited the 44 KB LDS allocation -> capped at 3 blocks/CU,
// 12+ turnover rounds of latency-bound tiny blocks). Zero LDS, grid-stride,
// full occupancy.
__global__ void cast_kernel(const float4* __restrict__ uf4,
                            const float4* __restrict__ itf4,
                            uint2* __restrict__ feats_out) {
    const int nuq  = NU_ * 16;
    const int totq = NTOT * 16;
    int stride = gridDim.x * 256;
    for (int i = blockIdx.x * 256 + threadIdx.x; i < totq; i += stride) {
        float4 v = (i < nuq) ? uf4[i] : itf4[i - nuq];
        uint2 o;
        o.x = pack2(v.x, v.y);
        o.y = pack2(v.z, v.w);
        feats_out[i] = o;
    }
}

// ---------------------------------------------------------------------------
// Multisplit only (staged private cells; R10 proved direct-scatter worse).
// DUAL-EMIT P branch (R11-proven): reads edges e < E_UI only, emits both
// directions. payload = ((row & 255) << 24) | col
__global__ void ms_kernel(const int* __restrict__ prows,
                          const int* __restrict__ pcols,
                          const int* __restrict__ brows,
                          const int* __restrict__ bcols,
                          unsigned int* __restrict__ binnedP,
                          int* __restrict__ cellcntP,
                          unsigned int* __restrict__ binnedB,
                          int* __restrict__ cellcntB) {
    constexpr int BUF = 16;
    __shared__ int cnt[NBIN_P];                 // staged-but-unflushed count
    __shared__ int fpos[NBIN_P];                // flushed count (cell-relative)
    __shared__ int basep[NBIN_P];               // flush base for current phase
    __shared__ unsigned int stage[NBIN_P][BUF];
    int bid = blockIdx.x;
    if (bid < VG_B) {
        // ------------------ B multisplit (4 slots/phase, R7-proven) -------
        int vb = bid;
        for (int i = threadIdx.x; i < NBIN_B; i += 256) { cnt[i] = 0; fpos[i] = 0; }
        __syncthreads();
        int stride = VG_B * 1024;
        for (int base = vb * 1024; base < E_BI_; base += stride) {
            int bin[4], pos[4];
            unsigned int payload[4];
            #pragma unroll
            for (int j = 0; j < 4; ++j) {
                int i = base + j * 256 + threadIdx.x;
                pos[j] = -1;
                if (i < E_BI_) {
                    int r = brows[i];
                    int c = bcols[i];
                    bin[j] = r >> 8;
                    payload[j] = ((unsigned int)(r & 255) << 24) | (unsigned int)c;
                    pos[j] = atomicAdd(&cnt[bin[j]], 1);
                    if (pos[j] < BUF) stage[bin[j]][pos[j]] = payload[j];
                }
            }
            __syncthreads();
            #pragma unroll
            for (int j = 0; j < 4; ++j)
                if (pos[j] == BUF) {           // unique leader per bin per phase
                    basep[bin[j]] = fpos[bin[j]];
                    fpos[bin[j]] += cnt[bin[j]];
                }
            __syncthreads();
            #pragma unroll
            for (int j = 0; j < 4; ++j) {
                if (pos[j] >= BUF) {
                    size_t cb = (size_t)bin[j] * BINSZ_B + (size_t)vb * SLICE_B;
                    int rel = basep[bin[j]] + pos[j];
                    if (rel < SLICE_B) binnedB[cb + rel] = payload[j];
                    if (pos[j] == BUF) {
                        int b0 = basep[bin[j]];
                        #pragma unroll
                        for (int q = 0; q < BUF; ++q)
                            if (b0 + q < SLICE_B) binnedB[cb + b0 + q] = stage[bin[j]][q];
                        cnt[bin[j]] = 0;
                    }
                }
            }
            __syncthreads();
        }
        for (int b = threadIdx.x; b < NBIN_B; b += 256) {
            int c = cnt[b];
            int f = fpos[b];
            size_t cb = (size_t)b * BINSZ_B + (size_t)vb * SLICE_B;
            for (int j = 0; j < c && f + j < SLICE_B; ++j) binnedB[cb + f + j] = stage[b][j];
            int tot = f + c;
            if (tot > SLICE_B) tot = SLICE_B;
            cellcntB[b * VG_B + vb] = tot;
        }
    } else {
        // ------------------ P multisplit: DUAL-EMIT, 8 slots/phase --------
        int vb = bid - VG_B;
        for (int i = threadIdx.x; i < NBIN_P; i += 256) { cnt[i] = 0; fpos[i] = 0; }
        __syncthreads();
        int stride = VG_P * 1024;
        for (int base = vb * 1024; base < E_UI_; base += stride) {
            int bin[8], pos[8];
            unsigned int payload[8];
            #pragma unroll
            for (int j = 0; j < 4; ++j) {
                int i = base + j * 256 + threadIdx.x;
                pos[2 * j] = -1;
                pos[2 * j + 1] = -1;
                if (i < E_UI_) {
                    int u   = prows[i];        // user row of edge i
                    int ipn = pcols[i];        // item row (+NU) of edge i
                    bin[2 * j] = u >> 8;
                    payload[2 * j] = ((unsigned int)(u & 255) << 24) | (unsigned int)ipn;
                    pos[2 * j] = atomicAdd(&cnt[bin[2 * j]], 1);
                    if (pos[2 * j] < BUF) stage[bin[2 * j]][pos[2 * j]] = payload[2 * j];
                    bin[2 * j + 1] = ipn >> 8;
                    payload[2 * j + 1] = ((unsigned int)(ipn & 255) << 24) | (unsigned int)u;
                    pos[2 * j + 1] = atomicAdd(&cnt[bin[2 * j + 1]], 1);
                    if (pos[2 * j + 1] < BUF) stage[bin[2 * j + 1]][pos[2 * j + 1]] = payload[2 * j + 1];
                }
            }
            __syncthreads();
            #pragma unroll
            for (int j = 0; j < 8; ++j)
                if (pos[j] == BUF) {           // unique leader per bin per phase
                    basep[bin[j]] = fpos[bin[j]];
                    fpos[bin[j]] += cnt[bin[j]];
                }
            __syncthreads();
            #pragma unroll
            for (int j = 0; j < 8; ++j) {
                if (pos[j] >= BUF) {
                    size_t cb = (size_t)bin[j] * BINSZ_P + (size_t)vb * SLICE_P;
                    int rel = basep[bin[j]] + pos[j];
                    if (rel < SLICE_P) binnedP[cb + rel] = payload[j];
                    if (pos[j] == BUF) {
                        int b0 = basep[bin[j]];
                        #pragma unroll
                        for (int q = 0; q < BUF; ++q)
                            if (b0 + q < SLICE_P) binnedP[cb + b0 + q] = stage[bin[j]][q];
                        cnt[bin[j]] = 0;
                    }
                }
            }
            __syncthreads();
        }
        for (int b = threadIdx.x; b < NBIN_P; b += 256) {
            int c = cnt[b];
            int f = fpos[b];
            size_t cb = (size_t)b * BINSZ_P + (size_t)vb * SLICE_P;
            for (int j = 0; j < c && f + j < SLICE_P; ++j) binnedP[cb + f + j] = stage[b][j];
            int tot = f + c;
            if (tot > SLICE_P) tot = SLICE_P;
            cellcntP[b * VG_P + vb] = tot;
        }
    }
}

// ---------------------------------------------------------------------------
// Per-bin CSR build, 512 threads/block. Two predicated coalesced sweeps,
// 4x unrolled (4 loads in flight per wave; R7 proved +30us vs 1-deep).
template<int VGRID, int SLICE>
__device__ __forceinline__ void bin_csr_body(unsigned int* __restrict__ binned,
                                             const int* __restrict__ cellcnt,
                                             int* __restrict__ off,
                                             int* __restrict__ deg,
                                             float* __restrict__ invs,
                                             int b, int nrows,
                                             unsigned int* ebuf, int* ccnt,
                                             int* cnt2, int* cnt, int* scanbuf) {
    const int TB = 512;
    const int total = VGRID * SLICE;
    int t = threadIdx.x;
    int rowbase = b << 8;
    for (int i = t; i < VGRID; i += TB) ccnt[i] = cellcnt[b * VGRID + i];
    for (int i = t; i < 256 * CSTRIDE; i += TB) cnt2[i] = 0;
    __syncthreads();
    size_t gbase = (size_t)b * total;
    // sweep 1: (row, chunk) histogram — 4 loads in flight
    for (int base = t; base < total; base += 4 * TB) {
        int i1 = base + TB, i2 = base + 2 * TB, i3 = base + 3 * TB;
        unsigned int p0 = binned[gbase + base];
        unsigned int p1 = (i1 < total) ? binned[gbase + i1] : 0u;
        unsigned int p2 = (i2 < total) ? binned[gbase + i2] : 0u;
        unsigned int p3 = (i3 < total) ? binned[gbase + i3] : 0u;
        {
            int cell = base / SLICE, rel = base - cell * SLICE;
            if (rel < ccnt[cell])
                atomicAdd(&cnt2[(int)(p0 >> 24) * CSTRIDE +
                                (int)((p0 & 0xFFFFFFu) >> CHK_SH)], 1);
        }
        if (i1 < total) {
            int cell = i1 / SLICE, rel = i1 - cell * SLICE;
            if (rel < ccnt[cell])
                atomicAdd(&cnt2[(int)(p1 >> 24) * CSTRIDE +
                                (int)((p1 & 0xFFFFFFu) >> CHK_SH)], 1);
        }
        if (i2 < total) {
            int cell = i2 / SLICE, rel = i2 - cell * SLICE;
            if (rel < ccnt[cell])
                atomicAdd(&cnt2[(int)(p2 >> 24) * CSTRIDE +
                                (int)((p2 & 0xFFFFFFu) >> CHK_SH)], 1);
        }
        if (i3 < total) {
            int cell = i3 / SLICE, rel = i3 - cell * SLICE;
            if (rel < ccnt[cell])
                atomicAdd(&cnt2[(int)(p3 >> 24) * CSTRIDE +
                                (int)((p3 & 0xFFFFFFu) >> CHK_SH)], 1);
        }
    }
    __syncthreads();
    // per-row totals, then exclusive scan of 256 row counts
    int x = 0;
    if (t < 256) {
        #pragma unroll
        for (int ch = 0; ch < NCHK; ++ch) x += cnt2[t * CSTRIDE + ch];
        cnt[t] = x;
        scanbuf[t] = x;
    }
    __syncthreads();
    for (int o = 1; o < 256; o <<= 1) {
        int y = 0;
        if (t < 256 && t >= o) y = scanbuf[t - o];
        __syncthreads();
        if (t < 256) scanbuf[t] += y;
        __syncthreads();
    }
    if (t < 256) {
        int base = scanbuf[t] - x;        // bin-local compact offset
        int c0 = base;
        #pragma unroll
        for (int ch = 0; ch < NCHK; ++ch) {
            int v = cnt2[t * CSTRIDE + ch];
            cnt2[t * CSTRIDE + ch] = c0;
            c0 += v;
        }
        if (rowbase + t < nrows) {
            off[rowbase + t] = (int)gbase + base;
            deg[rowbase + t] = x;
            if (invs) invs[rowbase + t] = 1.0f / (sqrtf((float)x) + 1e-8f);
        }
    }
    __syncthreads();
    int m = scanbuf[255];
    if (m > EBUF_CAP) m = EBUF_CAP;
    // sweep 2: place cols into ebuf at (row,chunk) cursor — 4 loads in flight
    for (int base = t; base < total; base += 4 * TB) {
        int i1 = base + TB, i2 = base + 2 * TB, i3 = base + 3 * TB;
        unsigned int p0 = binned[gbase + base];
        unsigned int p1 = (i1 < total) ? binned[gbase + i1] : 0u;
        unsigned int p2 = (i2 < total) ? binned[gbase + i2] : 0u;
        unsigned int p3 = (i3 < total) ? binned[gbase + i3] : 0u;
        {
            int cell = base / SLICE, rel = base - cell * SLICE;
            if (rel < ccnt[cell]) {
                unsigned int col = p0 & 0xFFFFFFu;
                int slot = atomicAdd(&cnt2[(int)(p0 >> 24) * CSTRIDE +
                                           (int)(col >> CHK_SH)], 1);
                if (slot < EBUF_CAP) ebuf[slot] = col;
            }
        }
        if (i1 < total) {
            int cell = i1 / SLICE, rel = i1 - cell * SLICE;
            if (rel < ccnt[cell]) {
                unsigned int col = p1 & 0xFFFFFFu;
                int slot = atomicAdd(&cnt2[(int)(p1 >> 24) * CSTRIDE +
                                           (int)(col >> CHK_SH)], 1);
                if (slot < EBUF_CAP) ebuf[slot] = col;
            }
        }
        if (i2 < total) {
            int cell = i2 / SLICE, rel = i2 - cell * SLICE;
            if (rel < ccnt[cell]) {
                unsigned int col = p2 & 0xFFFFFFu;
                int slot = atomicAdd(&cnt2[(int)(p2 >> 24) * CSTRIDE +
                                           (int)(col >> CHK_SH)], 1);
                if (slot < EBUF_CAP) ebuf[slot] = col;
            }
        }
        if (i3 < total) {
            int cell = i3 / SLICE, rel = i3 - cell * SLICE;
            if (rel < ccnt[cell]) {
                unsigned int col = p3 & 0xFFFFFFu;
                int slot = atomicAdd(&cnt2[(int)(p3 >> 24) * CSTRIDE +
                                           (int)(col >> CHK_SH)], 1);
                if (slot < EBUF_CAP) ebuf[slot] = col;
            }
        }
    }
    __syncthreads();
    // coalesced dump of the compacted prefix
    for (int i = t; i < m; i += TB) binned[gbase + i] = ebuf[i];
}

__global__ __launch_bounds__(512) void bin_csr_kernel(
        unsigned int* __restrict__ binnedP, const int* __restrict__ cellcntP,
        int* __restrict__ offP, int* __restrict__ degP, float* __restrict__ invsP,
        unsigned int* __restrict__ binnedB, const int* __restrict__ cellcntB,
        int* __restrict__ offB, int* __restrict__ degB) {
    __shared__ unsigned int ebuf[EBUF_CAP];    // 48 KB
    __shared__ int ccnt[VG_P];                 // 2 KB
    __shared__ int cnt2[256 * CSTRIDE];        // 11 KB (row,chunk) hist/cursor
    __shared__ int cnt[256];
    __shared__ int scanbuf[256];
    // grid order: [B bins][item bins 390..585][user bins 0..389]
    int b = blockIdx.x;
    if (b < NBIN_B) {
        bin_csr_body<VG_B, SLICE_B>(binnedB, cellcntB, offB, degB, (float*)0,
                                    b, NB_,
                                    ebuf, ccnt, cnt2, cnt, scanbuf);
    } else if (b < NBIN_B + NITEMBIN) {
        bin_csr_body<VG_P, SLICE_P>(binnedP, cellcntP, offP, degP, invsP,
                                    NUSERBIN + (b - NBIN_B), NTOT,
                                    ebuf, ccnt, cnt2, cnt, scanbuf);
    } else {
        bin_csr_body<VG_P, SLICE_P>(binnedP, cellcntP, offP, degP, invsP,
                                    b - (NBIN_B + NITEMBIN), NTOT,
                                    ebuf, ccnt, cnt2, cnt, scanbuf);
    }
}

// ---------------------------------------------------------------------------
// Streaming pre-scale + fp8 pack: g8[r] = e5m2(64 * invs[r] * feats16[r]).
// feats16 stays UNSCALED bf16 (layer1's identity term reads it directly).
__global__ void prescale_kernel(const float* __restrict__ invs,
                                const uint4* __restrict__ feats16,
                                uint2* __restrict__ g8) {
    int i = blockIdx.x * 256 + threadIdx.x;   // uint4/uint2 index, 8 per row
    if (i >= NTOT * 8) return;
    float iv = invs[i >> 3] * FP8SC;
    uint4 v = feats16[i];
    unsigned int lo = f2e5(iv * bflo(v.x))
                    | (f2e5(iv * bfhi(v.x)) << 8)
                    | (f2e5(iv * bflo(v.y)) << 16)
                    | (f2e5(iv * bfhi(v.y)) << 24);
    unsigned int hi = f2e5(iv * bflo(v.z))
                    | (f2e5(iv * bfhi(v.z)) << 8)
                    | (f2e5(iv * bflo(v.w)) << 16)
                    | (f2e5(iv * bfhi(v.w)) << 24);
    uint2 o; o.x = lo; o.y = hi;
    g8[i] = o;
}

// ---------------------------------------------------------------------------
__device__ __forceinline__ void fma8(float* s, float v, uint4 x) {
    s[0] = fmaf(v, bflo(x.x), s[0]);
    s[1] = fmaf(v, bfhi(x.x), s[1]);
    s[2] = fmaf(v, bflo(x.y), s[2]);
    s[3] = fmaf(v, bfhi(x.y), s[3]);
    s[4] = fmaf(v, bflo(x.z), s[4]);
    s[5] = fmaf(v, bfhi(x.z), s[5]);
    s[6] = fmaf(v, bflo(x.w), s[6]);
    s[7] = fmaf(v, bfhi(x.w), s[7]);
}
__device__ __forceinline__ uint4 pack8(const float* s) {
    uint4 o;
    o.x = pack2(s[0], s[1]);
    o.y = pack2(s[2], s[3]);
    o.z = pack2(s[4], s[5]);
    o.w = pack2(s[6], s[7]);
    return o;
}

// Layer 1 with fp8 gathers (g8 = e5m2(64*invs.*feats)):
//   sum_s = Σ g8[c]   (scaled by 64)
//   acc16[r] = feats16[r] + (invs[r]/64)*sum_s     (identity term full bf16)
//   f1s8[r]  = e5m2(invs[r]^2 * sum_s)             (= 64 * f1_true, exact fold)
__global__ void layer1_kernel(const int* __restrict__ off,
                              const int* __restrict__ deg,
                              const unsigned int* __restrict__ cv,
                              const uint2* __restrict__ g8,
                              const uint4* __restrict__ feats16,
                              uint2* __restrict__ f1s8,
                              uint4* __restrict__ acc16) {
    int wave = blockIdx.x * (blockDim.x >> 6) + (threadIdx.x >> 6);
    int sub  = (threadIdx.x >> 3) & 7;
    int l    = threadIdx.x & 7;
    int row  = wave * 8 + sub;
    if (row >= NTOT) return;
    int s = off[row], d = deg[row];
    float sum[8] = {0.f, 0.f, 0.f, 0.f, 0.f, 0.f, 0.f, 0.f};
    int k = 0;
    for (; k + 8 <= d; k += 8) {
        int c0 = (int)cv[s + k + 0];
        int c1 = (int)cv[s + k + 1];
        int c2 = (int)cv[s + k + 2];
        int c3 = (int)cv[s + k + 3];
        int c4 = (int)cv[s + k + 4];
        int c5 = (int)cv[s + k + 5];
        int c6 = (int)cv[s + k + 6];
        int c7 = (int)cv[s + k + 7];
        uint2 x0 = g8[(size_t)c0 * 8 + l];
        uint2 x1 = g8[(size_t)c1 * 8 + l];
        uint2 x2 = g8[(size_t)c2 * 8 + l];
        uint2 x3 = g8[(size_t)c3 * 8 + l];
        uint2 x4 = g8[(size_t)c4 * 8 + l];
        uint2 x5 = g8[(size_t)c5 * 8 + l];
        uint2 x6 = g8[(size_t)c6 * 8 + l];
        uint2 x7 = g8[(size_t)c7 * 8 + l];
        add8f8(sum, x0);
        add8f8(sum, x1);
        add8f8(sum, x2);
        add8f8(sum, x3);
        add8f8(sum, x4);
        add8f8(sum, x5);
        add8f8(sum, x6);
        add8f8(sum, x7);
    }
    for (; k < d; ++k) {
        int c = (int)cv[s + k];
        uint2 x = g8[(size_t)c * 8 + l];
        add8f8(sum, x);
    }
    float ivr = 1.0f / (sqrtf((float)d) + 1e-8f);
    uint4 bx = feats16[(size_t)row * 8 + l];
    float base[8] = {bflo(bx.x), bfhi(bx.x), bflo(bx.y), bfhi(bx.y),
                     bflo(bx.z), bfhi(bx.z), bflo(bx.w), bfhi(bx.w)};
    float a[8];
    float ivr_s = ivr * FP8ISC;
    float iv2   = ivr * ivr;
    #pragma unroll
    for (int j = 0; j < 8; ++j) a[j] = fmaf(ivr_s, sum[j], base[j]);
    uint2 fo;
    fo.x =  f2e5(iv2 * sum[0])
         | (f2e5(iv2 * sum[1]) << 8)
         | (f2e5(iv2 * sum[2]) << 16)
         | (f2e5(iv2 * sum[3]) << 24);
    fo.y =  f2e5(iv2 * sum[4])
         | (f2e5(iv2 * sum[5]) << 8)
         | (f2e5(iv2 * sum[6]) << 16)
         | (f2e5(iv2 * sum[7]) << 24);
    size_t idx = (size_t)row * 8 + l;
    acc16[idx] = pack8(a);
    f1s8[idx]  = fo;
}

// Layer 2 with fp8 gathers: acc16[r] += (invs[r]/64) * Σ f1s8[c]
// Row set restricted to what score reads: all item rows + sampled users.
__global__ void layer2_kernel(const int* __restrict__ off,
                              const int* __restrict__ deg,
                              const unsigned int* __restrict__ cv,
                              const float* __restrict__ invs,
                              const int* __restrict__ users,
                              const uint2* __restrict__ f1s8,
                              uint4* __restrict__ acc16) {
    int wave = blockIdx.x * (blockDim.x >> 6) + (threadIdx.x >> 6);
    int sub  = (threadIdx.x >> 3) & 7;
    int l    = threadIdx.x & 7;
    int ridx = wave * 8 + sub;
    if (ridx >= NROW2) return;
    int row = (ridx < NI_) ? (NU_ + ridx) : users[ridx - NI_];
    int s = off[row], d = deg[row];
    float sum[8] = {0.f, 0.f, 0.f, 0.f, 0.f, 0.f, 0.f, 0.f};
    int k = 0;
    for (; k + 8 <= d; k += 8) {
        int c0 = (int)cv[s + k + 0];
        int c1 = (int)cv[s + k + 1];
        int c2 = (int)cv[s + k + 2];
        int c3 = (int)cv[s + k + 3];
        int c4 = (int)cv[s + k + 4];
        int c5 = (int)cv[s + k + 5];
        int c6 = (int)cv[s + k + 6];
        int c7 = (int)cv[s + k + 7];
        uint2 x0 = f1s8[(size_t)c0 * 8 + l];
        uint2 x1 = f1s8[(size_t)c1 * 8 + l];
        uint2 x2 = f1s8[(size_t)c2 * 8 + l];
        uint2 x3 = f1s8[(size_t)c3 * 8 + l];
        uint2 x4 = f1s8[(size_t)c4 * 8 + l];
        uint2 x5 = f1s8[(size_t)c5 * 8 + l];
        uint2 x6 = f1s8[(size_t)c6 * 8 + l];
        uint2 x7 = f1s8[(size_t)c7 * 8 + l];
        add8f8(sum, x0);
        add8f8(sum, x1);
        add8f8(sum, x2);
        add8f8(sum, x3);
        add8f8(sum, x4);
        add8f8(sum, x5);
        add8f8(sum, x6);
        add8f8(sum, x7);
    }
    for (; k < d; ++k) {
        int c = (int)cv[s + k];
        uint2 x = f1s8[(size_t)c * 8 + l];
        add8f8(sum, x);
    }
    float ivr_s = invs[row] * FP8ISC;
    size_t idx = (size_t)row * 8 + l;
    uint4 ax = acc16[idx];
    float a[8] = {bflo(ax.x), bfhi(ax.x), bflo(ax.y), bfhi(ax.y),
                  bflo(ax.z), bfhi(ax.z), bflo(ax.w), bfhi(ax.w)};
    #pragma unroll
    for (int j = 0; j < 8; ++j) a[j] = fmaf(ivr_s, sum[j], a[j]);
    acc16[idx] = pack8(a);
}

// ---------------------------------------------------------------------------
// Fused bundle-SpMM + BPR loss + finalize. One wave per (sample, bundle).
__global__ void score_kernel(const int* __restrict__ offB,
                             const int* __restrict__ degB,
                             const unsigned int* __restrict__ cvB,
                             const uint4* __restrict__ acc16,
                             const int* __restrict__ users,
                             const int* __restrict__ bundles,
                             float* __restrict__ loss_sum,
                             int* __restrict__ done,
                             float* __restrict__ out) {
    __shared__ float sdp[4];
    int w    = threadIdx.x >> 6;          // wave within block (0..3)
    int wid  = blockIdx.x * 4 + w;        // global wave id
    int smp  = wid >> 1;                  // sample
    int j    = wid & 1;                   // bundle slot (0=pos, 1=neg)
    int lane = threadIdx.x & 63;
    int sub  = lane >> 3;                 // 8 subgroups of 8 lanes
    int l    = lane & 7;                  // dim slice [l*8, l*8+8)

    const uint4* items16 = acc16 + (size_t)NU_ * 8;

    int u  = users[smp];
    int bd = bundles[2 * smp + j];
    uint4 uv = acc16[(size_t)u * 8 + l];          // broadcast across subgroups
    int s = offB[bd];
    int d = degB[bd];

    // one coalesced load covers the first min(d,64) edge indices
    int dc = d < 64 ? d : 64;
    int cvec = 0;
    if (lane < dc) cvec = (int)cvB[s + lane];

    float part[8] = {0.f, 0.f, 0.f, 0.f, 0.f, 0.f, 0.f, 0.f};
    int nr = (dc + 7) >> 3;               // rounds of 8 edges
    for (int r = 0; r < nr; r += 4) {
        int i0 = (r + 0) * 8 + sub;
        int i1 = (r + 1) * 8 + sub;
        int i2 = (r + 2) * 8 + sub;
        int i3 = (r + 3) * 8 + sub;
        int c0 = __shfl(cvec, i0);
        int c1 = __shfl(cvec, i1);
        int c2 = __shfl(cvec, i2);
        int c3 = __shfl(cvec, i3);
        uint4 z; z.x = 0; z.y = 0; z.z = 0; z.w = 0;
        uint4 x0 = z, x1 = z, x2 = z, x3 = z;
        if (i0 < dc) x0 = items16[(size_t)c0 * 8 + l];   // 4 independent
        if (i1 < dc) x1 = items16[(size_t)c1 * 8 + l];   // gathers in flight
        if (i2 < dc) x2 = items16[(size_t)c2 * 8 + l];
        if (i3 < dc) x3 = items16[(size_t)c3 * 8 + l];
        fma8(part, 1.f, x0);
        fma8(part, 1.f, x1);
        fma8(part, 1.f, x2);
        fma8(part, 1.f, x3);
    }
    // rare tail: bundles with d > 64
    for (int k = 64 + sub; k < d; k += 8) {
        int c = (int)cvB[s + k];
        uint4 x = items16[(size_t)c * 8 + l];
        fma8(part, 1.f, x);
    }

    // reduce across the 8 subgroups (keeps dim slice l)
    #pragma unroll
    for (int m = 8; m <= 32; m <<= 1) {
        #pragma unroll
        for (int i = 0; i < 8; ++i)
            part[i] += __shfl_xor(part[i], m, 64);
    }
    float uvals[8] = {bflo(uv.x), bfhi(uv.x), bflo(uv.y), bfhi(uv.y),
                      bflo(uv.z), bfhi(uv.z), bflo(uv.w), bfhi(uv.w)};
    float dp = 0.f;
    #pragma unroll
    for (int i = 0; i < 8; ++i) dp = fmaf(part[i], uvals[i], dp);
    #pragma unroll
    for (int m = 1; m <= 4; m <<= 1)
        dp += __shfl_xor(dp, m, 64);
    dp = dp * (1.0f / 9.0f) / ((float)d + 1e-8f);

    if (lane == 0) sdp[w] = dp;
    __syncthreads();
    if (threadIdx.x == 0) {
        float x0 = sdp[0] - sdp[1];
        float x1 = sdp[2] - sdp[3];
        float lv = (fmaxf(-x0, 0.0f) + log1pf(expf(-fabsf(x0))))
                 + (fmaxf(-x1, 0.0f) + log1pf(expf(-fabsf(x1))));
        atomicAdd(loss_sum, lv);
        __threadfence();
        int old = atomicAdd(done, 1);
        if (old == (int)gridDim.x - 1) {
            float total = atomicAdd(loss_sum, 0.0f);   // coherent read
            out[0] = total * (1.0f / BATCH);
            out[1] = 0.0f;
        }
    }
}

// ---------------------------------------------------------------------------
extern "C" void kernel_launch(void* const* d_in, const int* in_sizes, int n_in,
                              void* d_out, int out_size, void* d_ws, size_t ws_size,
                              hipStream_t stream) {
    const float* uf        = (const float*)d_in[0];
    const float* itf       = (const float*)d_in[1];
    const int*   prop_rows = (const int*)  d_in[4];
    const int*   prop_cols = (const int*)  d_in[5];
    const int*   bi_rows   = (const int*)  d_in[6];
    const int*   bi_cols   = (const int*)  d_in[7];
    const int*   users     = (const int*)  d_in[8];
    const int*   bundles   = (const int*)  d_in[9];
    float* out = (float*)d_out;

    char* ws = (char*)d_ws;
    uint4*        acc16    = (uint4*)       (ws + 0);            // 19.2 MB bf16
    uint2*        f1s8     = (uint2*)       (ws + 19200000);     // 9.6 MB fp8
    uint2*        g8       = (uint2*)       (ws + 28800000);     // 9.6 MB fp8
    uint4*        feats16  = (uint4*)       (ws + 38400000);     // 19.2 MB bf16 (unscaled)
    unsigned int* binnedP  = (unsigned int*)(ws + 57600000);     // 48.0 MB
    unsigned int* binnedB  = (unsigned int*)(ws + 105605120);    // 4.85 MB
    int*          cellcntP = (int*)         (ws + 110458880);    // 1.2 MB
    int*          cellcntB = (int*)         (ws + 111659008);    // 30 KB
    int*          degP     = (int*)         (ws + 111689344);
    int*          offP     = (int*)         (ws + 112289344);
    float*        invsP    = (float*)       (ws + 112889344);
    int*          degB     = (int*)         (ws + 113489344);
    int*          offB     = (int*)         (ws + 113569344);
    float*        loss     = (float*)       (ws + 113649344);
    int*          done     = (int*)         (ws + 113649348);

    hipMemsetAsync(loss, 0, 8, stream);   // loss + done

    // 1a) streaming bf16 cast (no LDS, full occupancy)
    cast_kernel<<<CAST_BLOCKS, 256, 0, stream>>>(
        (const float4*)uf, (const float4*)itf, (uint2*)feats16);

    // 1b) multisplit (staged, dual-emit P), 608 co-resident blocks
    ms_kernel<<<MS_TOTAL, 256, 0, stream>>>(
        prop_rows, prop_cols, bi_rows, bi_cols,
        binnedP, cellcntP, binnedB, cellcntB);

    // 2) per-bin CSR build with column-chunk-ordered rows, heavy bins first,
    //    4-deep load pipelining in both sweeps
    bin_csr_kernel<<<NBIN_P + NBIN_B, 512, 0, stream>>>(
        binnedP, cellcntP, offP, degP, invsP,
        binnedB, cellcntB, offB, degB);

    // 2b) streaming pre-scale + fp8 pack (feats16 bf16 stays for identity term)
    prescale_kernel<<<(NTOT * 8 + 255) / 256, 256, 0, stream>>>(invsP, feats16, g8);

    // 3-4) propagation with fp8 gather payloads (halved L2-miss fill traffic)
    layer1_kernel<<<(NTOT + 31) / 32, 256, 0, stream>>>(offP, degP, binnedP,
                                                        g8, feats16, f1s8, acc16);
    layer2_kernel<<<(NROW2 + 31) / 32, 256, 0, stream>>>(offP, degP, binnedP, invsP,
                                                         users, f1s8, acc16);

    // 5) fused bundle-SpMM + loss + finalize (one wave per (sample,bundle))
    score_kernel<<<SCORE_BLOCKS, 256, 0, stream>>>(
        offB, degB, binnedB, acc16, users, bundles, loss, done, out);
}

// Round 14
// 310.125 us; speedup vs baseline: 1.1601x; 1.1601x over previous
//
#include <hip/hip_runtime.h>
#include <hip/hip_fp16.h>
#include <math.h>

#define NU_    100000
#define NI_    50000
#define NB_    20000
#define DIM    64
#define E_UI_  2000000
#define E_BI_  600000
#define NPROP  (2 * E_UI_)
#define NTOT   (NU_ + NI_)
#define BATCH  4096
#define NBIN_P ((NTOT + 255) / 256)   // 586
#define NBIN_B ((NB_  + 255) / 256)   // 79

// Private-cell multisplit geometry: binned[bin][block][slot].
#define VG_P     512
#define SLICE_P  40
#define BINSZ_P  (VG_P * SLICE_P)     // 20480 slots per P bin
#define VG_B     96
#define SLICE_B  160
#define BINSZ_B  (VG_B * SLICE_B)     // 15360 slots per B bin
// Bin populations are HETEROGENEOUS (lesson from R4/R5 crash):
//   user bins:  5120 +- 71, item bins: 10240 +- 101, B bins: 7680 +- 87
// EBUF_CAP must exceed the ITEM-bin tail: 12288 = 10240 + 20 sigma (proven).
#define EBUF_CAP 12288

// Column-chunk ordering for gather locality: granule 16384 rows = 2 MB.
#define CHK_SH   14
#define NCHK     ((NTOT >> CHK_SH) + 1)   // 10
#define CSTRIDE  11                       // padded row stride

// Heavy-bins-first grid order for bin_csr: [B(79), item(196), user(390)]
#define NITEMBIN 196
#define NUSERBIN 390

#define MS_TOTAL    (VG_B + VG_P)     // 608 multisplit blocks (all co-resident)
#define CAST_BLOCKS 2048              // grid-stride streaming cast, no LDS
#define SCORE_BLOCKS (BATCH / 2)      // 2048: one wave per (sample,bundle)

// Layer2 only needs rows that score reads: all items + the sampled users.
#define NROW2 (NI_ + BATCH)

// fp8 gather payload scale: g values std ~8e-4 are subnormal-adjacent in
// e5m2 (min normal 6.1e-5); x64 centers them in the normal range. The 64
// folds exactly through both layers (f1s8 stores 64*f1_true).
#define FP8SC   64.0f
#define FP8ISC  (1.0f / 64.0f)

// ---------------------------------------------------------------------------
// bf16 helpers
__device__ __forceinline__ float bflo(unsigned int u) {
    return __uint_as_float(u << 16);
}
__device__ __forceinline__ float bfhi(unsigned int u) {
    return __uint_as_float(u & 0xFFFF0000u);
}
__device__ __forceinline__ unsigned short f2bf(float f) {         // RNE
    unsigned int u = __float_as_uint(f);
    u += 0x7FFFu + ((u >> 16) & 1u);
    return (unsigned short)(u >> 16);
}
__device__ __forceinline__ unsigned int pack2(float a, float b) {
    return (unsigned int)f2bf(a) | ((unsigned int)f2bf(b) << 16);
}

// ---------------------------------------------------------------------------
// e5m2 helpers: an e5m2 byte IS the top byte of an f16.
__device__ __forceinline__ float e5b(unsigned int hbits) {   // hbits = f16 bits
    return __half2float(__ushort_as_half((unsigned short)hbits));
}
__device__ __forceinline__ unsigned int f2e5(float f) {      // RNE via f16
    unsigned short u = __half_as_ushort(__float2half(f));    // RNE to f16
    u = (unsigned short)(u + 0x7Fu + ((u >> 8) & 1u));       // RNE to top byte
    return (unsigned int)(u >> 8);
}
// decode 8 e5m2 bytes (uint2) and accumulate
__device__ __forceinline__ void add8f8(float* s, uint2 x) {
    s[0] += e5b((x.x << 8)  & 0xFF00u);
    s[1] += e5b( x.x        & 0xFF00u);
    s[2] += e5b((x.x >> 8)  & 0xFF00u);
    s[3] += e5b((x.x >> 16) & 0xFF00u);
    s[4] += e5b((x.y << 8)  & 0xFF00u);
    s[5] += e5b( x.y        & 0xFF00u);
    s[6] += e5b((x.y >> 8)  & 0xFF00u);
    s[7] += e5b((x.y >> 16) & 0xFF00u);
}

// ---------------------------------------------------------------------------
// Streaming bf16 cast (split from multisplit; zero LDS, full occupancy).
__global__ void cast_kernel(const float4* __restrict__ uf4,
                            const float4* __restrict__ itf4,
                            uint2* __restrict__ feats_out) {
    const int nuq  = NU_ * 16;
    const int totq = NTOT * 16;
    int stride = gridDim.x * 256;
    for (int i = blockIdx.x * 256 + threadIdx.x; i < totq; i += stride) {
        float4 v = (i < nuq) ? uf4[i] : itf4[i - nuq];
        uint2 o;
        o.x = pack2(v.x, v.y);
        o.y = pack2(v.z, v.w);
        feats_out[i] = o;
    }
}

// ---------------------------------------------------------------------------
// Multisplit only (staged private cells; R10 proved direct-scatter worse).
// DUAL-EMIT P branch (R11-proven): reads edges e < E_UI only, emits both
// directions. payload = ((row & 255) << 24) | col
__global__ void ms_kernel(const int* __restrict__ prows,
                          const int* __restrict__ pcols,
                          const int* __restrict__ brows,
                          const int* __restrict__ bcols,
                          unsigned int* __restrict__ binnedP,
                          int* __restrict__ cellcntP,
                          unsigned int* __restrict__ binnedB,
                          int* __restrict__ cellcntB) {
    constexpr int BUF = 16;
    __shared__ int cnt[NBIN_P];                 // staged-but-unflushed count
    __shared__ int fpos[NBIN_P];                // flushed count (cell-relative)
    __shared__ int basep[NBIN_P];               // flush base for current phase
    __shared__ unsigned int stage[NBIN_P][BUF];
    int bid = blockIdx.x;
    if (bid < VG_B) {
        // ------------------ B multisplit (4 slots/phase, R7-proven) -------
        int vb = bid;
        for (int i = threadIdx.x; i < NBIN_B; i += 256) { cnt[i] = 0; fpos[i] = 0; }
        __syncthreads();
        int stride = VG_B * 1024;
        for (int base = vb * 1024; base < E_BI_; base += stride) {
            int bin[4], pos[4];
            unsigned int payload[4];
            #pragma unroll
            for (int j = 0; j < 4; ++j) {
                int i = base + j * 256 + threadIdx.x;
                pos[j] = -1;
                if (i < E_BI_) {
                    int r = brows[i];
                    int c = bcols[i];
                    bin[j] = r >> 8;
                    payload[j] = ((unsigned int)(r & 255) << 24) | (unsigned int)c;
                    pos[j] = atomicAdd(&cnt[bin[j]], 1);
                    if (pos[j] < BUF) stage[bin[j]][pos[j]] = payload[j];
                }
            }
            __syncthreads();
            #pragma unroll
            for (int j = 0; j < 4; ++j)
                if (pos[j] == BUF) {           // unique leader per bin per phase
                    basep[bin[j]] = fpos[bin[j]];
                    fpos[bin[j]] += cnt[bin[j]];
                }
            __syncthreads();
            #pragma unroll
            for (int j = 0; j < 4; ++j) {
                if (pos[j] >= BUF) {
                    size_t cb = (size_t)bin[j] * BINSZ_B + (size_t)vb * SLICE_B;
                    int rel = basep[bin[j]] + pos[j];
                    if (rel < SLICE_B) binnedB[cb + rel] = payload[j];
                    if (pos[j] == BUF) {
                        int b0 = basep[bin[j]];
                        #pragma unroll
                        for (int q = 0; q < BUF; ++q)
                            if (b0 + q < SLICE_B) binnedB[cb + b0 + q] = stage[bin[j]][q];
                        cnt[bin[j]] = 0;
                    }
                }
            }
            __syncthreads();
        }
        for (int b = threadIdx.x; b < NBIN_B; b += 256) {
            int c = cnt[b];
            int f = fpos[b];
            size_t cb = (size_t)b * BINSZ_B + (size_t)vb * SLICE_B;
            for (int j = 0; j < c && f + j < SLICE_B; ++j) binnedB[cb + f + j] = stage[b][j];
            int tot = f + c;
            if (tot > SLICE_B) tot = SLICE_B;
            cellcntB[b * VG_B + vb] = tot;
        }
    } else {
        // ------------------ P multisplit: DUAL-EMIT, 8 slots/phase --------
        int vb = bid - VG_B;
        for (int i = threadIdx.x; i < NBIN_P; i += 256) { cnt[i] = 0; fpos[i] = 0; }
        __syncthreads();
        int stride = VG_P * 1024;
        for (int base = vb * 1024; base < E_UI_; base += stride) {
            int bin[8], pos[8];
            unsigned int payload[8];
            #pragma unroll
            for (int j = 0; j < 4; ++j) {
                int i = base + j * 256 + threadIdx.x;
                pos[2 * j] = -1;
                pos[2 * j + 1] = -1;
                if (i < E_UI_) {
                    int u   = prows[i];        // user row of edge i
                    int ipn = pcols[i];        // item row (+NU) of edge i
                    bin[2 * j] = u >> 8;
                    payload[2 * j] = ((unsigned int)(u & 255) << 24) | (unsigned int)ipn;
                    pos[2 * j] = atomicAdd(&cnt[bin[2 * j]], 1);
                    if (pos[2 * j] < BUF) stage[bin[2 * j]][pos[2 * j]] = payload[2 * j];
                    bin[2 * j + 1] = ipn >> 8;
                    payload[2 * j + 1] = ((unsigned int)(ipn & 255) << 24) | (unsigned int)u;
                    pos[2 * j + 1] = atomicAdd(&cnt[bin[2 * j + 1]], 1);
                    if (pos[2 * j + 1] < BUF) stage[bin[2 * j + 1]][pos[2 * j + 1]] = payload[2 * j + 1];
                }
            }
            __syncthreads();
            #pragma unroll
            for (int j = 0; j < 8; ++j)
                if (pos[j] == BUF) {           // unique leader per bin per phase
                    basep[bin[j]] = fpos[bin[j]];
                    fpos[bin[j]] += cnt[bin[j]];
                }
            __syncthreads();
            #pragma unroll
            for (int j = 0; j < 8; ++j) {
                if (pos[j] >= BUF) {
                    size_t cb = (size_t)bin[j] * BINSZ_P + (size_t)vb * SLICE_P;
                    int rel = basep[bin[j]] + pos[j];
                    if (rel < SLICE_P) binnedP[cb + rel] = payload[j];
                    if (pos[j] == BUF) {
                        int b0 = basep[bin[j]];
                        #pragma unroll
                        for (int q = 0; q < BUF; ++q)
                            if (b0 + q < SLICE_P) binnedP[cb + b0 + q] = stage[bin[j]][q];
                        cnt[bin[j]] = 0;
                    }
                }
            }
            __syncthreads();
        }
        for (int b = threadIdx.x; b < NBIN_P; b += 256) {
            int c = cnt[b];
            int f = fpos[b];
            size_t cb = (size_t)b * BINSZ_P + (size_t)vb * SLICE_P;
            for (int j = 0; j < c && f + j < SLICE_P; ++j) binnedP[cb + f + j] = stage[b][j];
            int tot = f + c;
            if (tot > SLICE_P) tot = SLICE_P;
            cellcntP[b * VG_P + vb] = tot;
        }
    }
}

// ---------------------------------------------------------------------------
// Per-bin CSR build, 512 threads/block. Two predicated coalesced sweeps,
// 4x unrolled (4 loads in flight per wave; R7 proved +30us vs 1-deep).
template<int VGRID, int SLICE>
__device__ __forceinline__ void bin_csr_body(unsigned int* __restrict__ binned,
                                             const int* __restrict__ cellcnt,
                                             int* __restrict__ off,
                                             int* __restrict__ deg,
                                             float* __restrict__ invs,
                                             int b, int nrows,
                                             unsigned int* ebuf, int* ccnt,
                                             int* cnt2, int* cnt, int* scanbuf) {
    const int TB = 512;
    const int total = VGRID * SLICE;
    int t = threadIdx.x;
    int rowbase = b << 8;
    for (int i = t; i < VGRID; i += TB) ccnt[i] = cellcnt[b * VGRID + i];
    for (int i = t; i < 256 * CSTRIDE; i += TB) cnt2[i] = 0;
    __syncthreads();
    size_t gbase = (size_t)b * total;
    // sweep 1: (row, chunk) histogram — 4 loads in flight
    for (int base = t; base < total; base += 4 * TB) {
        int i1 = base + TB, i2 = base + 2 * TB, i3 = base + 3 * TB;
        unsigned int p0 = binned[gbase + base];
        unsigned int p1 = (i1 < total) ? binned[gbase + i1] : 0u;
        unsigned int p2 = (i2 < total) ? binned[gbase + i2] : 0u;
        unsigned int p3 = (i3 < total) ? binned[gbase + i3] : 0u;
        {
            int cell = base / SLICE, rel = base - cell * SLICE;
            if (rel < ccnt[cell])
                atomicAdd(&cnt2[(int)(p0 >> 24) * CSTRIDE +
                                (int)((p0 & 0xFFFFFFu) >> CHK_SH)], 1);
        }
        if (i1 < total) {
            int cell = i1 / SLICE, rel = i1 - cell * SLICE;
            if (rel < ccnt[cell])
                atomicAdd(&cnt2[(int)(p1 >> 24) * CSTRIDE +
                                (int)((p1 & 0xFFFFFFu) >> CHK_SH)], 1);
        }
        if (i2 < total) {
            int cell = i2 / SLICE, rel = i2 - cell * SLICE;
            if (rel < ccnt[cell])
                atomicAdd(&cnt2[(int)(p2 >> 24) * CSTRIDE +
                                (int)((p2 & 0xFFFFFFu) >> CHK_SH)], 1);
        }
        if (i3 < total) {
            int cell = i3 / SLICE, rel = i3 - cell * SLICE;
            if (rel < ccnt[cell])
                atomicAdd(&cnt2[(int)(p3 >> 24) * CSTRIDE +
                                (int)((p3 & 0xFFFFFFu) >> CHK_SH)], 1);
        }
    }
    __syncthreads();
    // per-row totals, then exclusive scan of 256 row counts
    int x = 0;
    if (t < 256) {
        #pragma unroll
        for (int ch = 0; ch < NCHK; ++ch) x += cnt2[t * CSTRIDE + ch];
        cnt[t] = x;
        scanbuf[t] = x;
    }
    __syncthreads();
    for (int o = 1; o < 256; o <<= 1) {
        int y = 0;
        if (t < 256 && t >= o) y = scanbuf[t - o];
        __syncthreads();
        if (t < 256) scanbuf[t] += y;
        __syncthreads();
    }
    if (t < 256) {
        int base = scanbuf[t] - x;        // bin-local compact offset
        int c0 = base;
        #pragma unroll
        for (int ch = 0; ch < NCHK; ++ch) {
            int v = cnt2[t * CSTRIDE + ch];
            cnt2[t * CSTRIDE + ch] = c0;
            c0 += v;
        }
        if (rowbase + t < nrows) {
            off[rowbase + t] = (int)gbase + base;
            deg[rowbase + t] = x;
            if (invs) invs[rowbase + t] = 1.0f / (sqrtf((float)x) + 1e-8f);
        }
    }
    __syncthreads();
    int m = scanbuf[255];
    if (m > EBUF_CAP) m = EBUF_CAP;
    // sweep 2: place cols into ebuf at (row,chunk) cursor — 4 loads in flight
    for (int base = t; base < total; base += 4 * TB) {
        int i1 = base + TB, i2 = base + 2 * TB, i3 = base + 3 * TB;
        unsigned int p0 = binned[gbase + base];
        unsigned int p1 = (i1 < total) ? binned[gbase + i1] : 0u;
        unsigned int p2 = (i2 < total) ? binned[gbase + i2] : 0u;
        unsigned int p3 = (i3 < total) ? binned[gbase + i3] : 0u;
        {
            int cell = base / SLICE, rel = base - cell * SLICE;
            if (rel < ccnt[cell]) {
                unsigned int col = p0 & 0xFFFFFFu;
                int slot = atomicAdd(&cnt2[(int)(p0 >> 24) * CSTRIDE +
                                           (int)(col >> CHK_SH)], 1);
                if (slot < EBUF_CAP) ebuf[slot] = col;
            }
        }
        if (i1 < total) {
            int cell = i1 / SLICE, rel = i1 - cell * SLICE;
            if (rel < ccnt[cell]) {
                unsigned int col = p1 & 0xFFFFFFu;
                int slot = atomicAdd(&cnt2[(int)(p1 >> 24) * CSTRIDE +
                                           (int)(col >> CHK_SH)], 1);
                if (slot < EBUF_CAP) ebuf[slot] = col;
            }
        }
        if (i2 < total) {
            int cell = i2 / SLICE, rel = i2 - cell * SLICE;
            if (rel < ccnt[cell]) {
                unsigned int col = p2 & 0xFFFFFFu;
                int slot = atomicAdd(&cnt2[(int)(p2 >> 24) * CSTRIDE +
                                           (int)(col >> CHK_SH)], 1);
                if (slot < EBUF_CAP) ebuf[slot] = col;
            }
        }
        if (i3 < total) {
            int cell = i3 / SLICE, rel = i3 - cell * SLICE;
            if (rel < ccnt[cell]) {
                unsigned int col = p3 & 0xFFFFFFu;
                int slot = atomicAdd(&cnt2[(int)(p3 >> 24) * CSTRIDE +
                                           (int)(col >> CHK_SH)], 1);
                if (slot < EBUF_CAP) ebuf[slot] = col;
            }
        }
    }
    __syncthreads();
    // coalesced dump of the compacted prefix
    for (int i = t; i < m; i += TB) binned[gbase + i] = ebuf[i];
}

__global__ __launch_bounds__(512) void bin_csr_kernel(
        unsigned int* __restrict__ binnedP, const int* __restrict__ cellcntP,
        int* __restrict__ offP, int* __restrict__ degP, float* __restrict__ invsP,
        unsigned int* __restrict__ binnedB, const int* __restrict__ cellcntB,
        int* __restrict__ offB, int* __restrict__ degB) {
    __shared__ unsigned int ebuf[EBUF_CAP];    // 48 KB
    __shared__ int ccnt[VG_P];                 // 2 KB
    __shared__ int cnt2[256 * CSTRIDE];        // 11 KB (row,chunk) hist/cursor
    __shared__ int cnt[256];
    __shared__ int scanbuf[256];
    // grid order: [B bins][item bins 390..585][user bins 0..389]
    int b = blockIdx.x;
    if (b < NBIN_B) {
        bin_csr_body<VG_B, SLICE_B>(binnedB, cellcntB, offB, degB, (float*)0,
                                    b, NB_,
                                    ebuf, ccnt, cnt2, cnt, scanbuf);
    } else if (b < NBIN_B + NITEMBIN) {
        bin_csr_body<VG_P, SLICE_P>(binnedP, cellcntP, offP, degP, invsP,
                                    NUSERBIN + (b - NBIN_B), NTOT,
                                    ebuf, ccnt, cnt2, cnt, scanbuf);
    } else {
        bin_csr_body<VG_P, SLICE_P>(binnedP, cellcntP, offP, degP, invsP,
                                    b - (NBIN_B + NITEMBIN), NTOT,
                                    ebuf, ccnt, cnt2, cnt, scanbuf);
    }
}

// ---------------------------------------------------------------------------
// Streaming pre-scale + fp8 pack: g8[r] = e5m2(64 * invs[r] * feats16[r]).
// feats16 stays UNSCALED bf16 (layer1's identity term reads it directly).
__global__ void prescale_kernel(const float* __restrict__ invs,
                                const uint4* __restrict__ feats16,
                                uint2* __restrict__ g8) {
    int i = blockIdx.x * 256 + threadIdx.x;   // uint4/uint2 index, 8 per row
    if (i >= NTOT * 8) return;
    float iv = invs[i >> 3] * FP8SC;
    uint4 v = feats16[i];
    unsigned int lo = f2e5(iv * bflo(v.x))
                    | (f2e5(iv * bfhi(v.x)) << 8)
                    | (f2e5(iv * bflo(v.y)) << 16)
                    | (f2e5(iv * bfhi(v.y)) << 24);
    unsigned int hi = f2e5(iv * bflo(v.z))
                    | (f2e5(iv * bfhi(v.z)) << 8)
                    | (f2e5(iv * bflo(v.w)) << 16)
                    | (f2e5(iv * bfhi(v.w)) << 24);
    uint2 o; o.x = lo; o.y = hi;
    g8[i] = o;
}

// ---------------------------------------------------------------------------
__device__ __forceinline__ void fma8(float* s, float v, uint4 x) {
    s[0] = fmaf(v, bflo(x.x), s[0]);
    s[1] = fmaf(v, bfhi(x.x), s[1]);
    s[2] = fmaf(v, bflo(x.y), s[2]);
    s[3] = fmaf(v, bfhi(x.y), s[3]);
    s[4] = fmaf(v, bflo(x.z), s[4]);
    s[5] = fmaf(v, bfhi(x.z), s[5]);
    s[6] = fmaf(v, bflo(x.w), s[6]);
    s[7] = fmaf(v, bfhi(x.w), s[7]);
}
__device__ __forceinline__ uint4 pack8(const float* s) {
    uint4 o;
    o.x = pack2(s[0], s[1]);
    o.y = pack2(s[2], s[3]);
    o.z = pack2(s[4], s[5]);
    o.w = pack2(s[6], s[7]);
    return o;
}

// Layer 1 with fp8 gathers (g8 = e5m2(64*invs.*feats)):
//   sum_s = Σ g8[c]   (scaled by 64)
//   acc16[r] = feats16[r] + (invs[r]/64)*sum_s     (identity term full bf16)
//   f1s8[r]  = e5m2(invs[r]^2 * sum_s)             (= 64 * f1_true, exact fold)
__global__ void layer1_kernel(const int* __restrict__ off,
                              const int* __restrict__ deg,
                              const unsigned int* __restrict__ cv,
                              const uint2* __restrict__ g8,
                              const uint4* __restrict__ feats16,
                              uint2* __restrict__ f1s8,
                              uint4* __restrict__ acc16) {
    int wave = blockIdx.x * (blockDim.x >> 6) + (threadIdx.x >> 6);
    int sub  = (threadIdx.x >> 3) & 7;
    int l    = threadIdx.x & 7;
    int row  = wave * 8 + sub;
    if (row >= NTOT) return;
    int s = off[row], d = deg[row];
    float sum[8] = {0.f, 0.f, 0.f, 0.f, 0.f, 0.f, 0.f, 0.f};
    int k = 0;
    for (; k + 8 <= d; k += 8) {
        int c0 = (int)cv[s + k + 0];
        int c1 = (int)cv[s + k + 1];
        int c2 = (int)cv[s + k + 2];
        int c3 = (int)cv[s + k + 3];
        int c4 = (int)cv[s + k + 4];
        int c5 = (int)cv[s + k + 5];
        int c6 = (int)cv[s + k + 6];
        int c7 = (int)cv[s + k + 7];
        uint2 x0 = g8[(size_t)c0 * 8 + l];
        uint2 x1 = g8[(size_t)c1 * 8 + l];
        uint2 x2 = g8[(size_t)c2 * 8 + l];
        uint2 x3 = g8[(size_t)c3 * 8 + l];
        uint2 x4 = g8[(size_t)c4 * 8 + l];
        uint2 x5 = g8[(size_t)c5 * 8 + l];
        uint2 x6 = g8[(size_t)c6 * 8 + l];
        uint2 x7 = g8[(size_t)c7 * 8 + l];
        add8f8(sum, x0);
        add8f8(sum, x1);
        add8f8(sum, x2);
        add8f8(sum, x3);
        add8f8(sum, x4);
        add8f8(sum, x5);
        add8f8(sum, x6);
        add8f8(sum, x7);
    }
    for (; k < d; ++k) {
        int c = (int)cv[s + k];
        uint2 x = g8[(size_t)c * 8 + l];
        add8f8(sum, x);
    }
    float ivr = 1.0f / (sqrtf((float)d) + 1e-8f);
    uint4 bx = feats16[(size_t)row * 8 + l];
    float base[8] = {bflo(bx.x), bfhi(bx.x), bflo(bx.y), bfhi(bx.y),
                     bflo(bx.z), bfhi(bx.z), bflo(bx.w), bfhi(bx.w)};
    float a[8];
    float ivr_s = ivr * FP8ISC;
    float iv2   = ivr * ivr;
    #pragma unroll
    for (int j = 0; j < 8; ++j) a[j] = fmaf(ivr_s, sum[j], base[j]);
    uint2 fo;
    fo.x =  f2e5(iv2 * sum[0])
         | (f2e5(iv2 * sum[1]) << 8)
         | (f2e5(iv2 * sum[2]) << 16)
         | (f2e5(iv2 * sum[3]) << 24);
    fo.y =  f2e5(iv2 * sum[4])
         | (f2e5(iv2 * sum[5]) << 8)
         | (f2e5(iv2 * sum[6]) << 16)
         | (f2e5(iv2 * sum[7]) << 24);
    size_t idx = (size_t)row * 8 + l;
    acc16[idx] = pack8(a);
    f1s8[idx]  = fo;
}

// Layer 2 with fp8 gathers: acc16[r] += (invs[r]/64) * Σ f1s8[c]
// Row set restricted to what score reads: all item rows + sampled users.
__global__ void layer2_kernel(const int* __restrict__ off,
                              const int* __restrict__ deg,
                              const unsigned int* __restrict__ cv,
                              const float* __restrict__ invs,
                              const int* __restrict__ users,
                              const uint2* __restrict__ f1s8,
                              uint4* __restrict__ acc16) {
    int wave = blockIdx.x * (blockDim.x >> 6) + (threadIdx.x >> 6);
    int sub  = (threadIdx.x >> 3) & 7;
    int l    = threadIdx.x & 7;
    int ridx = wave * 8 + sub;
    if (ridx >= NROW2) return;
    int row = (ridx < NI_) ? (NU_ + ridx) : users[ridx - NI_];
    int s = off[row], d = deg[row];
    float sum[8] = {0.f, 0.f, 0.f, 0.f, 0.f, 0.f, 0.f, 0.f};
    int k = 0;
    for (; k + 8 <= d; k += 8) {
        int c0 = (int)cv[s + k + 0];
        int c1 = (int)cv[s + k + 1];
        int c2 = (int)cv[s + k + 2];
        int c3 = (int)cv[s + k + 3];
        int c4 = (int)cv[s + k + 4];
        int c5 = (int)cv[s + k + 5];
        int c6 = (int)cv[s + k + 6];
        int c7 = (int)cv[s + k + 7];
        uint2 x0 = f1s8[(size_t)c0 * 8 + l];
        uint2 x1 = f1s8[(size_t)c1 * 8 + l];
        uint2 x2 = f1s8[(size_t)c2 * 8 + l];
        uint2 x3 = f1s8[(size_t)c3 * 8 + l];
        uint2 x4 = f1s8[(size_t)c4 * 8 + l];
        uint2 x5 = f1s8[(size_t)c5 * 8 + l];
        uint2 x6 = f1s8[(size_t)c6 * 8 + l];
        uint2 x7 = f1s8[(size_t)c7 * 8 + l];
        add8f8(sum, x0);
        add8f8(sum, x1);
        add8f8(sum, x2);
        add8f8(sum, x3);
        add8f8(sum, x4);
        add8f8(sum, x5);
        add8f8(sum, x6);
        add8f8(sum, x7);
    }
    for (; k < d; ++k) {
        int c = (int)cv[s + k];
        uint2 x = f1s8[(size_t)c * 8 + l];
        add8f8(sum, x);
    }
    float ivr_s = invs[row] * FP8ISC;
    size_t idx = (size_t)row * 8 + l;
    uint4 ax = acc16[idx];
    float a[8] = {bflo(ax.x), bfhi(ax.x), bflo(ax.y), bfhi(ax.y),
                  bflo(ax.z), bfhi(ax.z), bflo(ax.w), bfhi(ax.w)};
    #pragma unroll
    for (int j = 0; j < 8; ++j) a[j] = fmaf(ivr_s, sum[j], a[j]);
    acc16[idx] = pack8(a);
}

// ---------------------------------------------------------------------------
// Fused bundle-SpMM + BPR loss. One wave per (sample, bundle).
// ATOMIC-FREE EPILOGUE (R13 post-mortem): the old epilogue issued 4096
// same-cache-line global atomics (loss at +0, done at +4) -> ~15 ns/op
// serialized ~= the entire 60 us kernel duration. Now each block stores its
// 2-sample partial loss to partials[blockIdx.x]; a tiny finalize kernel sums.
__global__ void score_kernel(const int* __restrict__ offB,
                             const int* __restrict__ degB,
                             const unsigned int* __restrict__ cvB,
                             const uint4* __restrict__ acc16,
                             const int* __restrict__ users,
                             const int* __restrict__ bundles,
                             float* __restrict__ partials) {
    __shared__ float sdp[4];
    int w    = threadIdx.x >> 6;          // wave within block (0..3)
    int wid  = blockIdx.x * 4 + w;        // global wave id
    int smp  = wid >> 1;                  // sample
    int j    = wid & 1;                   // bundle slot (0=pos, 1=neg)
    int lane = threadIdx.x & 63;
    int sub  = lane >> 3;                 // 8 subgroups of 8 lanes
    int l    = lane & 7;                  // dim slice [l*8, l*8+8)

    const uint4* items16 = acc16 + (size_t)NU_ * 8;

    int u  = users[smp];
    int bd = bundles[2 * smp + j];
    uint4 uv = acc16[(size_t)u * 8 + l];          // broadcast across subgroups
    int s = offB[bd];
    int d = degB[bd];

    // one coalesced load covers the first min(d,64) edge indices
    int dc = d < 64 ? d : 64;
    int cvec = 0;
    if (lane < dc) cvec = (int)cvB[s + lane];

    float part[8] = {0.f, 0.f, 0.f, 0.f, 0.f, 0.f, 0.f, 0.f};
    int nr = (dc + 7) >> 3;               // rounds of 8 edges
    for (int r = 0; r < nr; r += 4) {
        int i0 = (r + 0) * 8 + sub;
        int i1 = (r + 1) * 8 + sub;
        int i2 = (r + 2) * 8 + sub;
        int i3 = (r + 3) * 8 + sub;
        int c0 = __shfl(cvec, i0);
        int c1 = __shfl(cvec, i1);
        int c2 = __shfl(cvec, i2);
        int c3 = __shfl(cvec, i3);
        uint4 z; z.x = 0; z.y = 0; z.z = 0; z.w = 0;
        uint4 x0 = z, x1 = z, x2 = z, x3 = z;
        if (i0 < dc) x0 = items16[(size_t)c0 * 8 + l];   // 4 independent
        if (i1 < dc) x1 = items16[(size_t)c1 * 8 + l];   // gathers in flight
        if (i2 < dc) x2 = items16[(size_t)c2 * 8 + l];
        if (i3 < dc) x3 = items16[(size_t)c3 * 8 + l];
        fma8(part, 1.f, x0);
        fma8(part, 1.f, x1);
        fma8(part, 1.f, x2);
        fma8(part, 1.f, x3);
    }
    // rare tail: bundles with d > 64
    for (int k = 64 + sub; k < d; k += 8) {
        int c = (int)cvB[s + k];
        uint4 x = items16[(size_t)c * 8 + l];
        fma8(part, 1.f, x);
    }

    // reduce across the 8 subgroups (keeps dim slice l)
    #pragma unroll
    for (int m = 8; m <= 32; m <<= 1) {
        #pragma unroll
        for (int i = 0; i < 8; ++i)
            part[i] += __shfl_xor(part[i], m, 64);
    }
    float uvals[8] = {bflo(uv.x), bfhi(uv.x), bflo(uv.y), bfhi(uv.y),
                      bflo(uv.z), bfhi(uv.z), bflo(uv.w), bfhi(uv.w)};
    float dp = 0.f;
    #pragma unroll
    for (int i = 0; i < 8; ++i) dp = fmaf(part[i], uvals[i], dp);
    #pragma unroll
    for (int m = 1; m <= 4; m <<= 1)
        dp += __shfl_xor(dp, m, 64);
    dp = dp * (1.0f / 9.0f) / ((float)d + 1e-8f);

    if (lane == 0) sdp[w] = dp;
    __syncthreads();
    if (threadIdx.x == 0) {
        float x0 = sdp[0] - sdp[1];
        float x1 = sdp[2] - sdp[3];
        float lv = (fmaxf(-x0, 0.0f) + log1pf(expf(-fabsf(x0))))
                 + (fmaxf(-x1, 0.0f) + log1pf(expf(-fabsf(x1))));
        partials[blockIdx.x] = lv;        // plain store, no atomics, no fence
    }
}

// Tiny tree-reduction of the 2048 block partials -> final loss.
__global__ void finalize_kernel(const float* __restrict__ partials,
                                float* __restrict__ out) {
    __shared__ float red[256];
    float s = 0.f;
    for (int i = threadIdx.x; i < SCORE_BLOCKS; i += 256) s += partials[i];
    red[threadIdx.x] = s;
    __syncthreads();
    for (int o = 128; o > 0; o >>= 1) {
        if (threadIdx.x < o) red[threadIdx.x] += red[threadIdx.x + o];
        __syncthreads();
    }
    if (threadIdx.x == 0) {
        out[0] = red[0] * (1.0f / BATCH);
        out[1] = 0.0f;
    }
}

// ---------------------------------------------------------------------------
extern "C" void kernel_launch(void* const* d_in, const int* in_sizes, int n_in,
                              void* d_out, int out_size, void* d_ws, size_t ws_size,
                              hipStream_t stream) {
    const float* uf        = (const float*)d_in[0];
    const float* itf       = (const float*)d_in[1];
    const int*   prop_rows = (const int*)  d_in[4];
    const int*   prop_cols = (const int*)  d_in[5];
    const int*   bi_rows   = (const int*)  d_in[6];
    const int*   bi_cols   = (const int*)  d_in[7];
    const int*   users     = (const int*)  d_in[8];
    const int*   bundles   = (const int*)  d_in[9];
    float* out = (float*)d_out;

    char* ws = (char*)d_ws;
    uint4*        acc16    = (uint4*)       (ws + 0);            // 19.2 MB bf16
    uint2*        f1s8     = (uint2*)       (ws + 19200000);     // 9.6 MB fp8
    uint2*        g8       = (uint2*)       (ws + 28800000);     // 9.6 MB fp8
    uint4*        feats16  = (uint4*)       (ws + 38400000);     // 19.2 MB bf16 (unscaled)
    unsigned int* binnedP  = (unsigned int*)(ws + 57600000);     // 48.0 MB
    unsigned int* binnedB  = (unsigned int*)(ws + 105605120);    // 4.85 MB
    int*          cellcntP = (int*)         (ws + 110458880);    // 1.2 MB
    int*          cellcntB = (int*)         (ws + 111659008);    // 30 KB
    int*          degP     = (int*)         (ws + 111689344);
    int*          offP     = (int*)         (ws + 112289344);
    float*        invsP    = (float*)       (ws + 112889344);
    int*          degB     = (int*)         (ws + 113489344);
    int*          offB     = (int*)         (ws + 113569344);
    float*        partials = (float*)       (ws + 113649344);    // 8 KB

    // 1a) streaming bf16 cast (no LDS, full occupancy)
    cast_kernel<<<CAST_BLOCKS, 256, 0, stream>>>(
        (const float4*)uf, (const float4*)itf, (uint2*)feats16);

    // 1b) multisplit (staged, dual-emit P), 608 co-resident blocks
    ms_kernel<<<MS_TOTAL, 256, 0, stream>>>(
        prop_rows, prop_cols, bi_rows, bi_cols,
        binnedP, cellcntP, binnedB, cellcntB);

    // 2) per-bin CSR build with column-chunk-ordered rows, heavy bins first,
    //    4-deep load pipelining in both sweeps
    bin_csr_kernel<<<NBIN_P + NBIN_B, 512, 0, stream>>>(
        binnedP, cellcntP, offP, degP, invsP,
        binnedB, cellcntB, offB, degB);

    // 2b) streaming pre-scale + fp8 pack (feats16 bf16 stays for identity term)
    prescale_kernel<<<(NTOT * 8 + 255) / 256, 256, 0, stream>>>(invsP, feats16, g8);

    // 3-4) propagation with fp8 gather payloads (halved L2-miss fill traffic)
    layer1_kernel<<<(NTOT + 31) / 32, 256, 0, stream>>>(offP, degP, binnedP,
                                                        g8, feats16, f1s8, acc16);
    layer2_kernel<<<(NROW2 + 31) / 32, 256, 0, stream>>>(offP, degP, binnedP, invsP,
                                                         users, f1s8, acc16);

    // 5) fused bundle-SpMM + loss (atomic-free partials) + tree finalize
    score_kernel<<<SCORE_BLOCKS, 256, 0, stream>>>(
        offB, degB, binnedB, acc16, users, bundles, partials);
    finalize_kernel<<<1, 256, 0, stream>>>(partials, out);
}